// Round 1
// baseline (44.129 us; speedup 1.0000x reference)
//
#include <hip/hip_runtime.h>
#include <math.h>

#define NV      6890
#define VFLOATS (NV * 3)          // 20670 floats = 82680 B
#define BLOCK   1024
#define NWAVES  (BLOCK / 64)
#define DENSITY 985.0f
#define EPS     1e-12f

__global__ __launch_bounds__(BLOCK) void measure_kernel(
    const float* __restrict__ v,        // (B, NV, 3)
    const int*   __restrict__ faces,    // (F, 3)
    const int*   __restrict__ circ_idx, // (3,)
    const int*   __restrict__ h_idx,    // (2,)
    float*       __restrict__ out,      // (B, 5)
    int F)
{
    extern __shared__ float lds[];              // VFLOATS verts + NWAVES*4 reduce
    float* red = lds + VFLOATS;

    const int b = blockIdx.x;
    const float* vb = v + (size_t)b * VFLOATS;

    // stage this batch's vertices into LDS (coalesced)
    for (int i = threadIdx.x; i < VFLOATS; i += BLOCK)
        lds[i] = vb[i];
    __syncthreads();

    // plane y's (LDS broadcast — all lanes same address)
    float pys[3];
    pys[0] = lds[circ_idx[0] * 3 + 1];
    pys[1] = lds[circ_idx[1] * 3 + 1];
    pys[2] = lds[circ_idx[2] * 3 + 1];

    float vol = 0.0f;
    float circ0 = 0.0f, circ1 = 0.0f, circ2 = 0.0f;

    for (int f = threadIdx.x; f < F; f += BLOCK) {
        const int i0 = faces[3 * f + 0];
        const int i1 = faces[3 * f + 1];
        const int i2 = faces[3 * f + 2];

        const float x0 = lds[3 * i0], y0 = lds[3 * i0 + 1], z0 = lds[3 * i0 + 2];
        const float x1 = lds[3 * i1], y1 = lds[3 * i1 + 1], z1 = lds[3 * i1 + 2];
        const float x2 = lds[3 * i2], y2 = lds[3 * i2 + 1], z2 = lds[3 * i2 + 2];

        // signed volume term: v0 . (v1 x v2)
        {
            const float cx = y1 * z2 - z1 * y2;
            const float cy = z1 * x2 - x1 * z2;
            const float cz = x1 * y2 - y1 * x2;
            vol += x0 * cx + y0 * cy + z0 * cz;
        }

        // circumference per plane
        #pragma unroll
        for (int p = 0; p < 3; ++p) {
            const float py = pys[p];
            const float d0 = y0 - py;
            const float d1 = y1 - py;
            const float d2 = y2 - py;
            const bool c0 = (d0 * d1) < 0.0f;   // edge v0->v1
            const bool c1 = (d1 * d2) < 0.0f;   // edge v1->v2
            const bool c2 = (d2 * d0) < 0.0f;   // edge v2->v0

            if (!((c0 && c1) || (c1 && c2) || (c2 && c0))) continue;

            float q0x = 0.f, q0y = 0.f, q0z = 0.f;
            float q1x = 0.f, q1y = 0.f, q1z = 0.f;
            float q2x = 0.f, q2y = 0.f, q2z = 0.f;
            if (c0) {
                const float t = d0 / (d0 - d1);
                q0x = x0 + t * (x1 - x0); q0y = y0 + t * (y1 - y0); q0z = z0 + t * (z1 - z0);
            }
            if (c1) {
                const float t = d1 / (d1 - d2);
                q1x = x1 + t * (x2 - x1); q1y = y1 + t * (y2 - y1); q1z = z1 + t * (z2 - z1);
            }
            if (c2) {
                const float t = d2 / (d2 - d0);
                q2x = x2 + t * (x0 - x2); q2y = y2 + t * (y0 - y2); q2z = z2 + t * (z0 - z2);
            }

            float s = 0.0f;
            if (c0 && c1) {
                const float dx = q1x - q0x, dy = q1y - q0y, dz = q1z - q0z;
                s += sqrtf(dx * dx + dy * dy + dz * dz + EPS);
            }
            if (c1 && c2) {
                const float dx = q2x - q1x, dy = q2y - q1y, dz = q2z - q1z;
                s += sqrtf(dx * dx + dy * dy + dz * dz + EPS);
            }
            if (c2 && c0) {
                const float dx = q0x - q2x, dy = q0y - q2y, dz = q0z - q2z;
                s += sqrtf(dx * dx + dy * dy + dz * dz + EPS);
            }
            if (p == 0) circ0 += s;
            else if (p == 1) circ1 += s;
            else circ2 += s;
        }
    }

    // wave-level reduction (wave = 64)
    #pragma unroll
    for (int off = 32; off > 0; off >>= 1) {
        vol   += __shfl_down(vol,   off);
        circ0 += __shfl_down(circ0, off);
        circ1 += __shfl_down(circ1, off);
        circ2 += __shfl_down(circ2, off);
    }
    const int lane = threadIdx.x & 63;
    const int wid  = threadIdx.x >> 6;
    if (lane == 0) {
        red[wid * 4 + 0] = vol;
        red[wid * 4 + 1] = circ0;
        red[wid * 4 + 2] = circ1;
        red[wid * 4 + 3] = circ2;
    }
    __syncthreads();

    if (threadIdx.x == 0) {
        float tv = 0.f, t0 = 0.f, t1 = 0.f, t2 = 0.f;
        for (int w = 0; w < NWAVES; ++w) {
            tv += red[w * 4 + 0];
            t0 += red[w * 4 + 1];
            t1 += red[w * 4 + 2];
            t2 += red[w * 4 + 3];
        }
        const float mass = fabsf(tv / 6.0f) * DENSITY;
        const float hy0 = lds[h_idx[0] * 3 + 1];
        const float hy1 = lds[h_idx[1] * 3 + 1];
        out[b * 5 + 0] = mass;
        out[b * 5 + 1] = fabsf(hy0 - hy1);
        out[b * 5 + 2] = t0;
        out[b * 5 + 3] = t1;
        out[b * 5 + 4] = t2;
    }
}

extern "C" void kernel_launch(void* const* d_in, const int* in_sizes, int n_in,
                              void* d_out, int out_size, void* d_ws, size_t ws_size,
                              hipStream_t stream) {
    const float* v        = (const float*)d_in[0];
    const int*   faces    = (const int*)d_in[1];
    const int*   circ_idx = (const int*)d_in[2];
    const int*   h_idx    = (const int*)d_in[3];
    float*       out      = (float*)d_out;

    const int B = in_sizes[0] / VFLOATS;   // 256
    const int F = in_sizes[1] / 3;         // 13776

    const size_t lds_bytes = (size_t)(VFLOATS + NWAVES * 4) * sizeof(float);
    measure_kernel<<<B, BLOCK, lds_bytes, stream>>>(v, faces, circ_idx, h_idx, out, F);
}

// Round 2
// 23.627 us; speedup vs baseline: 1.8677x; 1.8677x over previous
//
#include <hip/hip_runtime.h>
#include <math.h>

#define NV      6890
#define BLOCK   1024
#define NWAVES  (BLOCK / 64)
#define DENSITY 985.0f
#define EPS     1e-12f

__device__ __forceinline__ float frcp(float x)  { return __builtin_amdgcn_rcpf(x); }
__device__ __forceinline__ float fsqrt(float x) { return __builtin_amdgcn_sqrtf(x); }

__global__ __launch_bounds__(BLOCK) void measure_kernel(
    const float* __restrict__ v,        // (B, NV, 3)
    const int*   __restrict__ faces,    // (F, 3)
    const int*   __restrict__ circ_idx, // (3,)
    const int*   __restrict__ h_idx,    // (2,)
    float*       __restrict__ out,      // (B, 5)
    int F)
{
    extern __shared__ float lds[];              // NV float4 verts + NWAVES*4 reduce
    float4* vert = reinterpret_cast<float4*>(lds);
    float*  red  = lds + NV * 4;

    const int b = blockIdx.x;
    const float* vb = v + (size_t)b * NV * 3;

    // stage this batch's vertices into LDS, padded to float4 (one ds_write_b128 each)
    for (int i = threadIdx.x; i < NV; i += BLOCK) {
        const float* p = vb + 3 * i;
        vert[i] = make_float4(p[0], p[1], p[2], 0.0f);
    }
    __syncthreads();

    // plane y's (LDS broadcast)
    const float py0 = vert[circ_idx[0]].y;
    const float py1 = vert[circ_idx[1]].y;
    const float py2 = vert[circ_idx[2]].y;
    const float pys[3] = {py0, py1, py2};

    float vol = 0.0f;
    float circ[3] = {0.0f, 0.0f, 0.0f};

    #pragma unroll 2
    for (int f = threadIdx.x; f < F; f += BLOCK) {
        const int i0 = faces[3 * f + 0];
        const int i1 = faces[3 * f + 1];
        const int i2 = faces[3 * f + 2];

        const float4 V0 = vert[i0];
        const float4 V1 = vert[i1];
        const float4 V2 = vert[i2];

        // signed volume term: v0 . (v1 x v2)
        {
            const float cx = V1.y * V2.z - V1.z * V2.y;
            const float cy = V1.z * V2.x - V1.x * V2.z;
            const float cz = V1.x * V2.y - V1.y * V2.x;
            vol += V0.x * cx + V0.y * cy + V0.z * cz;
        }

        // circumference per plane — fully branchless.
        // At most one consecutive edge-pair can cross (signs can't alternate
        // three times around a triangle), so select that segment and do one sqrt.
        #pragma unroll
        for (int p = 0; p < 3; ++p) {
            const float py = pys[p];
            const float d0 = V0.y - py;
            const float d1 = V1.y - py;
            const float d2 = V2.y - py;
            const bool c0 = (d0 * d1) < 0.0f;   // edge v0->v1
            const bool c1 = (d1 * d2) < 0.0f;   // edge v1->v2
            const bool c2 = (d2 * d0) < 0.0f;   // edge v2->v0

            // fast rcp; garbage (inf/nan) t is never selected
            const float t0 = d0 * frcp(d0 - d1);
            const float t1 = d1 * frcp(d1 - d2);
            const float t2 = d2 * frcp(d2 - d0);

            // intersection points (x,z only — y == py up to rounding)
            const float q0x = fmaf(t0, V1.x - V0.x, V0.x);
            const float q0z = fmaf(t0, V1.z - V0.z, V0.z);
            const float q1x = fmaf(t1, V2.x - V1.x, V1.x);
            const float q1z = fmaf(t1, V2.z - V1.z, V1.z);
            const float q2x = fmaf(t2, V0.x - V2.x, V2.x);
            const float q2z = fmaf(t2, V0.z - V2.z, V2.z);

            const bool p0 = c0 && c1;           // segment q0 -> q1
            const bool p1 = c1 && c2;           // segment q1 -> q2
            const bool p2 = c2 && c0;           // segment q2 -> q0
            const bool any = p0 || p1 || p2;

            const float qAx = p0 ? q0x : (p1 ? q1x : q2x);
            const float qAz = p0 ? q0z : (p1 ? q1z : q2z);
            const float qBx = p0 ? q1x : (p1 ? q2x : q0x);
            const float qBz = p0 ? q1z : (p1 ? q2z : q0z);

            const float dx = qBx - qAx;
            const float dz = qBz - qAz;
            const float L  = fsqrt(fmaf(dx, dx, fmaf(dz, dz, EPS)));
            circ[p] += any ? L : 0.0f;
        }
    }

    // wave-level reduction (wave = 64)
    #pragma unroll
    for (int off = 32; off > 0; off >>= 1) {
        vol     += __shfl_down(vol,     off);
        circ[0] += __shfl_down(circ[0], off);
        circ[1] += __shfl_down(circ[1], off);
        circ[2] += __shfl_down(circ[2], off);
    }
    const int lane = threadIdx.x & 63;
    const int wid  = threadIdx.x >> 6;
    if (lane == 0) {
        red[wid * 4 + 0] = vol;
        red[wid * 4 + 1] = circ[0];
        red[wid * 4 + 2] = circ[1];
        red[wid * 4 + 3] = circ[2];
    }
    __syncthreads();

    if (threadIdx.x == 0) {
        float tv = 0.f, t0 = 0.f, t1 = 0.f, t2 = 0.f;
        for (int w = 0; w < NWAVES; ++w) {
            tv += red[w * 4 + 0];
            t0 += red[w * 4 + 1];
            t1 += red[w * 4 + 2];
            t2 += red[w * 4 + 3];
        }
        const float mass = fabsf(tv / 6.0f) * DENSITY;
        const float hy0 = vert[h_idx[0]].y;
        const float hy1 = vert[h_idx[1]].y;
        out[b * 5 + 0] = mass;
        out[b * 5 + 1] = fabsf(hy0 - hy1);
        out[b * 5 + 2] = t0;
        out[b * 5 + 3] = t1;
        out[b * 5 + 4] = t2;
    }
}

extern "C" void kernel_launch(void* const* d_in, const int* in_sizes, int n_in,
                              void* d_out, int out_size, void* d_ws, size_t ws_size,
                              hipStream_t stream) {
    const float* v        = (const float*)d_in[0];
    const int*   faces    = (const int*)d_in[1];
    const int*   circ_idx = (const int*)d_in[2];
    const int*   h_idx    = (const int*)d_in[3];
    float*       out      = (float*)d_out;

    const int B = in_sizes[0] / (NV * 3);   // 256
    const int F = in_sizes[1] / 3;          // 13776

    const size_t lds_bytes = (size_t)(NV * 4 + NWAVES * 4) * sizeof(float);
    measure_kernel<<<B, BLOCK, lds_bytes, stream>>>(v, faces, circ_idx, h_idx, out, F);
}

// Round 3
// 19.651 us; speedup vs baseline: 2.2456x; 1.2024x over previous
//
#include <hip/hip_runtime.h>
#include <math.h>

#define NV      6890
#define BLOCK   1024
#define NWAVES  (BLOCK / 64)
#define DENSITY 985.0f
#define EPS     1e-12f

typedef float v2f __attribute__((ext_vector_type(2)));

__device__ __forceinline__ float frcp(float x)  { return __builtin_amdgcn_rcpf(x); }
__device__ __forceinline__ float fsqrt(float x) { return __builtin_amdgcn_sqrtf(x); }

__global__ __launch_bounds__(BLOCK) void measure_kernel(
    const float* __restrict__ v,        // (B, NV, 3)
    const int*   __restrict__ faces,    // (F, 3)
    const int*   __restrict__ circ_idx, // (3,)
    const int*   __restrict__ h_idx,    // (2,)
    float*       __restrict__ out,      // (B, 5)
    int F)
{
    extern __shared__ float lds[];              // NV float4 verts + NWAVES*4 reduce
    float4* vert = reinterpret_cast<float4*>(lds);
    float*  red  = lds + NV * 4;

    const int b = blockIdx.x;
    const float* vb = v + (size_t)b * NV * 3;

    // stage this batch's vertices into LDS, padded to float4
    for (int i = threadIdx.x; i < NV; i += BLOCK) {
        const float* p = vb + 3 * i;
        vert[i] = make_float4(p[0], p[1], p[2], 0.0f);
    }
    __syncthreads();

    const float pys[3] = { vert[circ_idx[0]].y,
                           vert[circ_idx[1]].y,
                           vert[circ_idx[2]].y };

    float vol = 0.0f;
    float circ[3] = {0.0f, 0.0f, 0.0f};

    #pragma unroll 2
    for (int f = threadIdx.x; f < F; f += BLOCK) {
        const int i0 = faces[3 * f + 0];
        const int i1 = faces[3 * f + 1];
        const int i2 = faces[3 * f + 2];

        const float4 V0 = vert[i0];
        const float4 V1 = vert[i1];
        const float4 V2 = vert[i2];

        // signed volume term: v0 . (v1 x v2)
        {
            const float cx = V1.y * V2.z - V1.z * V2.y;
            const float cy = V1.z * V2.x - V1.x * V2.z;
            const float cz = V1.x * V2.y - V1.y * V2.x;
            vol += V0.x * cx + V0.y * cy + V0.z * cz;
        }

        // ---- plane-invariant edge data (hoisted out of the plane loop) ----
        // t_e(p) = (ya - py) / (ya - yb), denominator is plane-independent.
        const float r01 = frcp(V0.y - V1.y);
        const float r12 = frcp(V1.y - V2.y);
        const float r20 = frcp(V2.y - V0.y);

        const v2f xz0 = { V0.x, V0.z };
        const v2f xz1 = { V1.x, V1.z };
        const v2f xz2 = { V2.x, V2.z };
        const v2f e01 = xz1 - xz0;   // packed fp32
        const v2f e12 = xz2 - xz1;
        const v2f e20 = xz0 - xz2;

        // y == py on both endpoints up to rounding; segment uses (x,z) only.
        #pragma unroll
        for (int p = 0; p < 3; ++p) {
            const float py = pys[p];
            const float d0 = V0.y - py;
            const float d1 = V1.y - py;
            const float d2 = V2.y - py;
            const bool c0 = (d0 * d1) < 0.0f;   // edge v0->v1 crosses
            const bool c1 = (d1 * d2) < 0.0f;   // edge v1->v2
            const bool c2 = (d2 * d0) < 0.0f;   // edge v2->v0

            const float t0 = d0 * r01;          // garbage unless selected
            const float t1 = d1 * r12;
            const float t2 = d2 * r20;

            const v2f q0 = t0 * e01 + xz0;      // v_pk_fma_f32
            const v2f q1 = t1 * e12 + xz1;
            const v2f q2 = t2 * e20 + xz2;

            // Crossings come in pairs (0 or exactly 2 edges cross):
            // endpoints are {q_i : c_i}.  qA = c0?q0:q1, qB = c2?q2:q1.
            const v2f qA = c0 ? q0 : q1;
            const v2f qB = c2 ? q2 : q1;
            const bool any = c0 || c1 || c2;

            const v2f  d  = qA - qB;
            const float L = fsqrt(fmaf(d.x, d.x, fmaf(d.y, d.y, EPS)));
            circ[p] += any ? L : 0.0f;
        }
    }

    // wave-level reduction (wave = 64)
    #pragma unroll
    for (int off = 32; off > 0; off >>= 1) {
        vol     += __shfl_down(vol,     off);
        circ[0] += __shfl_down(circ[0], off);
        circ[1] += __shfl_down(circ[1], off);
        circ[2] += __shfl_down(circ[2], off);
    }
    const int lane = threadIdx.x & 63;
    const int wid  = threadIdx.x >> 6;
    if (lane == 0) {
        red[wid * 4 + 0] = vol;
        red[wid * 4 + 1] = circ[0];
        red[wid * 4 + 2] = circ[1];
        red[wid * 4 + 3] = circ[2];
    }
    __syncthreads();

    if (threadIdx.x == 0) {
        float tv = 0.f, t0 = 0.f, t1 = 0.f, t2 = 0.f;
        for (int w = 0; w < NWAVES; ++w) {
            tv += red[w * 4 + 0];
            t0 += red[w * 4 + 1];
            t1 += red[w * 4 + 2];
            t2 += red[w * 4 + 3];
        }
        const float mass = fabsf(tv / 6.0f) * DENSITY;
        const float hy0 = vert[h_idx[0]].y;
        const float hy1 = vert[h_idx[1]].y;
        out[b * 5 + 0] = mass;
        out[b * 5 + 1] = fabsf(hy0 - hy1);
        out[b * 5 + 2] = t0;
        out[b * 5 + 3] = t1;
        out[b * 5 + 4] = t2;
    }
}

extern "C" void kernel_launch(void* const* d_in, const int* in_sizes, int n_in,
                              void* d_out, int out_size, void* d_ws, size_t ws_size,
                              hipStream_t stream) {
    const float* v        = (const float*)d_in[0];
    const int*   faces    = (const int*)d_in[1];
    const int*   circ_idx = (const int*)d_in[2];
    const int*   h_idx    = (const int*)d_in[3];
    float*       out      = (float*)d_out;

    const int B = in_sizes[0] / (NV * 3);   // 256
    const int F = in_sizes[1] / 3;          // 13776

    const size_t lds_bytes = (size_t)(NV * 4 + NWAVES * 4) * sizeof(float);
    measure_kernel<<<B, BLOCK, lds_bytes, stream>>>(v, faces, circ_idx, h_idx, out, F);
}